// Round 1
// baseline (2421.743 us; speedup 1.0000x reference)
//
#include <hip/hip_runtime.h>
#include <math.h>

#define N_NODES 50000
#define E_EDGES 1600000
#define F_IN    2000
#define D       20
#define NCOL    160   // 2 edge types * 4 matrices (q,k,v,s) * 20

#define INV_SQRT_D 0.22360679774997896f

// ---------------- pack weights into [K][160] layout + zero accumulators ----------------
__global__ void pack_kernel(
    const float* __restrict__ W0q, const float* __restrict__ W0k,
    const float* __restrict__ W0v, const float* __restrict__ W0s,
    const float* __restrict__ b0q, const float* __restrict__ b0k,
    const float* __restrict__ b0v, const float* __restrict__ b0s,
    const float* __restrict__ Wq,  const float* __restrict__ Wk,
    const float* __restrict__ Wv,  const float* __restrict__ Ws_,
    const float* __restrict__ bq,  const float* __restrict__ bk,
    const float* __restrict__ bv,  const float* __restrict__ bs_,
    float* __restrict__ B0, float* __restrict__ bias0,
    float* __restrict__ WL, float* __restrict__ biasL,
    float* __restrict__ bn, int* __restrict__ deg)
{
  long idx = (long)blockIdx.x * blockDim.x + threadIdx.x;
  if (idx < 320000) {                       // B0: [2000][160]
    int k = (int)(idx / NCOL), col = (int)(idx % NCOL);
    int et = col / 80, r = col % 80, mat = r / 20, d = r % 20;
    const float* w = (mat==0)?W0q:(mat==1)?W0k:(mat==2)?W0v:W0s;
    B0[idx] = w[((size_t)et*F_IN + k)*D + d];
    return;
  }
  idx -= 320000;
  if (idx < 160) {                          // bias0
    int col = (int)idx;
    int et = col / 80, r = col % 80, mat = r / 20, d = r % 20;
    const float* b = (mat==0)?b0q:(mat==1)?b0k:(mat==2)?b0v:b0s;
    bias0[col] = b[et*D + d];
    return;
  }
  idx -= 160;
  if (idx < 9600) {                         // WL: 3 x [20][160]
    int l = (int)(idx / 3200), rem = (int)(idx % 3200);
    int k = rem / NCOL, col = rem % NCOL;
    int et = col / 80, r = col % 80, mat = r / 20, d = r % 20;
    const float* w = (mat==0)?Wq:(mat==1)?Wk:(mat==2)?Wv:Ws_;
    WL[idx] = w[(((size_t)l*2 + et)*D + k)*D + d];
    return;
  }
  idx -= 9600;
  if (idx < 480) {                          // biasL: 3 x [160]
    int l = (int)(idx / NCOL), col = (int)(idx % NCOL);
    int et = col / 80, r = col % 80, mat = r / 20, d = r % 20;
    const float* b = (mat==0)?bq:(mat==1)?bk:(mat==2)?bv:bs_;
    biasL[idx] = b[(l*2 + et)*D + d];
    return;
  }
  idx -= 480;
  if (idx < 320) { bn[idx] = 0.f; return; } // BN accumulators, 4 layers x 80
  idx -= 320;
  if (idx < 2*N_NODES) { deg[idx] = 0; return; }
}

// ---------------- CSR build (indices are static across layers -> build once per call) ---
__global__ void hist_kernel(const int* __restrict__ same, const int* __restrict__ diff,
                            int* __restrict__ deg)
{
  long i = (long)blockIdx.x * blockDim.x + threadIdx.x;
  if (i >= 2L*E_EDGES) return;
  int et = (i >= E_EDGES) ? 1 : 0;
  long e = i - (long)et*E_EDGES;
  const int* ix = et ? diff : same;
  int dst = ix[E_EDGES + e];
  atomicAdd(&deg[(size_t)et*N_NODES + dst], 1);
}

__global__ void scan_kernel(const int* __restrict__ deg,
                            int* __restrict__ rowptr0, int* __restrict__ rowptr1,
                            int* __restrict__ next0, int* __restrict__ next1)
{
  const int et = blockIdx.x;
  const int* dg = deg + (size_t)et*N_NODES;
  int* rp = et ? rowptr1 : rowptr0;
  int* np = et ? next1 : next0;
  __shared__ int part[1024];
  const int t = threadIdx.x;
  const int per = (N_NODES + 1023) / 1024;  // 49
  const int b = t * per;
  const int e = (b + per < N_NODES) ? (b + per) : N_NODES;
  int s = 0;
  for (int i = b; i < e; i++) s += dg[i];
  part[t] = s;
  __syncthreads();
  for (int o = 1; o < 1024; o <<= 1) {
    int v = (t >= o) ? part[t-o] : 0;
    __syncthreads();
    part[t] += v;
    __syncthreads();
  }
  int run = (t == 0) ? 0 : part[t-1];
  for (int i = b; i < e; i++) {
    rp[i] = run; np[i] = run;
    run += dg[i];
  }
  if (t == 0) rp[N_NODES] = part[1023];
}

__global__ void scatter_kernel(const int* __restrict__ same, const int* __restrict__ diff,
                               int* __restrict__ next0, int* __restrict__ next1,
                               int* __restrict__ adj0, int* __restrict__ adj1)
{
  long i = (long)blockIdx.x * blockDim.x + threadIdx.x;
  if (i >= 2L*E_EDGES) return;
  int et = (i >= E_EDGES) ? 1 : 0;
  long e = i - (long)et*E_EDGES;
  const int* ix = et ? diff : same;
  int src = ix[e];
  int dst = ix[E_EDGES + e];
  int* np  = et ? next1 : next0;
  int* adj = et ? adj1  : adj0;
  int pos = atomicAdd(&np[dst], 1);
  adj[pos] = src;
}

// ---------------- layer-0 projection GEMM: [50000,2000] @ [2000,160] + bias -------------
__launch_bounds__(256)
__global__ void gemm0_kernel(const float* __restrict__ A,
                             const float* __restrict__ B,
                             const float* __restrict__ bias,
                             float* __restrict__ C)
{
  __shared__ float as[64*44];    // 64 x 40, stride 44 (pad: bank spread, keeps 16B align)
  __shared__ float bs[160*44];   // transposed B tile: [col][kk], stride 44
  const int t = threadIdx.x;
  const int rb0 = blockIdx.x * 64;
  const int rbase = (t >> 4) * 4;   // 0..60
  const int c0 = t & 15;

  float acc[4][10];
#pragma unroll
  for (int i = 0; i < 4; i++)
#pragma unroll
    for (int j = 0; j < 10; j++) acc[i][j] = 0.f;

  for (int k0 = 0; k0 < F_IN; k0 += 40) {
#pragma unroll
    for (int i = 0; i < 10; i++) {       // A tile: 64*40 = 2560
      int idx = t + i*256;
      int r = idx / 40, c = idx % 40;
      int gr = rb0 + r;
      as[r*44 + c] = (gr < N_NODES) ? A[(size_t)gr*F_IN + k0 + c] : 0.f;
    }
#pragma unroll
    for (int i = 0; i < 25; i++) {       // B tile: 40*160 = 6400 -> transposed
      int idx = t + i*256;
      int kk = idx / NCOL, col = idx % NCOL;
      bs[col*44 + kk] = B[(size_t)(k0 + kk)*NCOL + col];
    }
    __syncthreads();
#pragma unroll
    for (int kk = 0; kk < 40; kk += 4) {
      float4 av[4];
#pragma unroll
      for (int i = 0; i < 4; i++) av[i] = *(const float4*)&as[(rbase + i)*44 + kk];
      float4 bv[10];
#pragma unroll
      for (int j = 0; j < 10; j++) bv[j] = *(const float4*)&bs[(c0 + 16*j)*44 + kk];
#pragma unroll
      for (int i = 0; i < 4; i++)
#pragma unroll
        for (int j = 0; j < 10; j++) {
          acc[i][j] += av[i].x * bv[j].x;
          acc[i][j] += av[i].y * bv[j].y;
          acc[i][j] += av[i].z * bv[j].z;
          acc[i][j] += av[i].w * bv[j].w;
        }
    }
    __syncthreads();
  }
#pragma unroll
  for (int i = 0; i < 4; i++) {
    int r = rb0 + rbase + i;
    if (r < N_NODES) {
#pragma unroll
      for (int j = 0; j < 10; j++) {
        int c = c0 + 16*j;
        C[(size_t)r*NCOL + c] = acc[i][j] + bias[c];
      }
    }
  }
}

// ---------------- layers 1..3 projection: [N,20] @ [20,160] + bias ----------------------
__launch_bounds__(256)
__global__ void proj_small_kernel(const float* __restrict__ x, const float* __restrict__ W,
                                  const float* __restrict__ bias, float* __restrict__ C)
{
  __shared__ float ws[20*160];
  __shared__ float xs[16*20];
  const int t = threadIdx.x;
  const int n0 = blockIdx.x * 16;
#pragma unroll
  for (int i = 0; i < 13; i++) {
    int idx = t + i*256;
    if (idx < 3200) ws[idx] = W[idx];
  }
#pragma unroll
  for (int i = 0; i < 2; i++) {
    int idx = t + i*256;
    if (idx < 320) {
      int nl = idx / 20, k = idx % 20;
      int n = n0 + nl;
      xs[idx] = (n < N_NODES) ? x[(size_t)n*D + k] : 0.f;
    }
  }
  __syncthreads();
#pragma unroll
  for (int i = 0; i < 10; i++) {
    int idx = t + i*256;
    int nl = idx / NCOL, col = idx % NCOL;
    int n = n0 + nl;
    if (n < N_NODES) {
      float acc = bias[col];
#pragma unroll
      for (int k = 0; k < 20; k++) acc += xs[nl*20 + k] * ws[k*NCOL + col];
      C[(size_t)n*NCOL + col] = acc;
    }
  }
}

// ---------------- gather-based attention: one wave per dst node -------------------------
__launch_bounds__(256)
__global__ void attn_kernel(const int* __restrict__ rowptr,
                            const int* __restrict__ adj,
                            const float* __restrict__ proj,
                            int et, float* __restrict__ xout)
{
  const int wid  = blockIdx.x * 4 + (threadIdx.x >> 6);
  const int lane = threadIdx.x & 63;
  if (wid >= N_NODES) return;

  const size_t rowb = (size_t)wid*NCOL + (size_t)et*80;
  float4 qv[5];
#pragma unroll
  for (int j = 0; j < 5; j++) qv[j] = *(const float4*)(proj + rowb + 4*j);

  const int beg = rowptr[wid], end = rowptr[wid+1];

  // pass 1: exact max of q.k
  float mx = -INFINITY;
  for (int i = beg + lane; i < end; i += 64) {
    const float* kp = proj + (size_t)adj[i]*NCOL + (size_t)et*80 + 20;
    float acc = 0.f;
#pragma unroll
    for (int j = 0; j < 5; j++) {
      float4 kv = *(const float4*)(kp + 4*j);
      acc += qv[j].x*kv.x + qv[j].y*kv.y + qv[j].z*kv.z + qv[j].w*kv.w;
    }
    mx = fmaxf(mx, acc);
  }
#pragma unroll
  for (int o = 32; o > 0; o >>= 1) mx = fmaxf(mx, __shfl_xor(mx, o, 64));
  const float m = mx * INV_SQRT_D;

  // pass 2: exp-sum and weighted V accumulate (per lane, then butterfly)
  float zl = 0.f;
  float S[20];
#pragma unroll
  for (int d = 0; d < 20; d++) S[d] = 0.f;

  for (int i = beg + lane; i < end; i += 64) {
    const int src = adj[i];
    const float* kp = proj + (size_t)src*NCOL + (size_t)et*80 + 20;
    float acc = 0.f;
#pragma unroll
    for (int j = 0; j < 5; j++) {
      float4 kv = *(const float4*)(kp + 4*j);
      acc += qv[j].x*kv.x + qv[j].y*kv.y + qv[j].z*kv.z + qv[j].w*kv.w;
    }
    const float w = expf(acc*INV_SQRT_D - m);
    zl += w;
    const float* vp = proj + (size_t)src*NCOL + (size_t)et*80 + 40;
#pragma unroll
    for (int j = 0; j < 5; j++) {
      float4 vv = *(const float4*)(vp + 4*j);
      S[4*j+0] += w*vv.x; S[4*j+1] += w*vv.y; S[4*j+2] += w*vv.z; S[4*j+3] += w*vv.w;
    }
  }
#pragma unroll
  for (int o = 32; o > 0; o >>= 1) {
    zl += __shfl_xor(zl, o, 64);
#pragma unroll
    for (int d = 0; d < 20; d++) S[d] += __shfl_xor(S[d], o, 64);
  }
  if (lane == 0) {
    const float inv = 1.f / (zl + 1e-16f);
    const float* sp = proj + rowb + 60;   // skip term x@Ws+bs
    float* xo = xout + (size_t)wid*D;
#pragma unroll
    for (int j = 0; j < 5; j++) {
      float4 sv = *(const float4*)(sp + 4*j);
      float4 o4;
      o4.x = S[4*j+0]*inv + sv.x;
      o4.y = S[4*j+1]*inv + sv.y;
      o4.z = S[4*j+2]*inv + sv.z;
      o4.w = S[4*j+3]*inv + sv.w;
      *(float4*)(xo + 4*j) = o4;
    }
  }
}

// ---------------- combine edge types + BN partial sums ----------------------------------
__global__ void combine_kernel(const float* __restrict__ A0, const float* __restrict__ A1,
                               const float* __restrict__ w1, const float* __restrict__ w2,
                               int l, float* __restrict__ xpre, float* __restrict__ bn)
{
  __shared__ float ls[40];
  const int t = threadIdx.x;
  if (t < 40) ls[t] = 0.f;
  __syncthreads();
  const int i = blockIdx.x*256 + t;
  if (i < N_NODES*D) {
    float a = w1[l], b = w2[l];
    float tt = a + b;
    float v = (a/tt)*A0[i] + (b/tt)*A1[i];
    xpre[i] = v;
    int d = i % D;
    atomicAdd(&ls[d], v);
    atomicAdd(&ls[20+d], v*v);
  }
  __syncthreads();
  if (t < 40) atomicAdd(&bn[t], ls[t]);
}

__global__ void stats_kernel(float* __restrict__ bn)
{
  int t = threadIdx.x;
  if (t < D) {
    float mu  = bn[t] * (1.f/N_NODES);
    float var = bn[20+t] * (1.f/N_NODES) - mu*mu;
    bn[40+t] = mu;
    bn[60+t] = 1.f / sqrtf(var + 1e-5f);
  }
}

__global__ void bnapply_kernel(const float* __restrict__ xpre, const float* __restrict__ bn,
                               const float* __restrict__ gamma, const float* __restrict__ beta,
                               int l, float* __restrict__ out)
{
  const int i = blockIdx.x*256 + threadIdx.x;
  if (i >= N_NODES*D) return;
  const int d = i % D;
  float v = (xpre[i] - bn[40+d]) * bn[60+d] * gamma[l*D+d] + beta[l*D+d];
  out[i] = (v > 0.f) ? v : 0.01f*v;
}

// ---------------- final: concat(fcs) @ Wout + bout --------------------------------------
__global__ void final_kernel(const float* __restrict__ fcs, const float* __restrict__ Wout,
                             const float* __restrict__ bout, float* __restrict__ out)
{
  const int n = blockIdx.x*256 + threadIdx.x;
  if (n >= N_NODES) return;
  float a0 = bout[0], a1 = bout[1];
#pragma unroll
  for (int l = 0; l < 4; l++) {
    const float* base = fcs + (size_t)l*N_NODES*D + (size_t)n*D;
#pragma unroll
    for (int d = 0; d < D; d++) {
      float v = base[d];
      a0 += v * Wout[(l*D+d)*2 + 0];
      a1 += v * Wout[(l*D+d)*2 + 1];
    }
  }
  out[n*2+0] = a0;
  out[n*2+1] = a1;
}

// ----------------------------------------------------------------------------------------
extern "C" void kernel_launch(void* const* d_in, const int* in_sizes, int n_in,
                              void* d_out, int out_size, void* d_ws, size_t ws_size,
                              hipStream_t stream)
{
  const float* feat = (const float*)d_in[0];
  const int*   same = (const int*)d_in[1];
  const int*   diff = (const int*)d_in[2];
  const float* W0q = (const float*)d_in[3];
  const float* b0q = (const float*)d_in[4];
  const float* W0k = (const float*)d_in[5];
  const float* b0k = (const float*)d_in[6];
  const float* W0v = (const float*)d_in[7];
  const float* b0v = (const float*)d_in[8];
  const float* W0s = (const float*)d_in[9];
  const float* b0s = (const float*)d_in[10];
  const float* Wq  = (const float*)d_in[11];
  const float* bq  = (const float*)d_in[12];
  const float* Wk  = (const float*)d_in[13];
  const float* bk  = (const float*)d_in[14];
  const float* Wv  = (const float*)d_in[15];
  const float* bv  = (const float*)d_in[16];
  const float* Ws_ = (const float*)d_in[17];
  const float* bs_ = (const float*)d_in[18];
  const float* w1  = (const float*)d_in[19];
  const float* w2  = (const float*)d_in[20];
  const float* gamma = (const float*)d_in[21];
  const float* beta  = (const float*)d_in[22];
  const float* Wout  = (const float*)d_in[23];
  const float* bout  = (const float*)d_in[24];

  float* wsf  = (float*)d_ws;
  float* PROJ  = wsf;                      // 8,000,000  [N][160]
  float* A0    = wsf + 8000000;            // 1,000,000  [N][20]
  float* A1    = wsf + 9000000;            // 1,000,000
  float* XPRE  = wsf + 10000000;           // 1,000,000
  float* FCS   = wsf + 11000000;           // 4,000,000  [4][N][20]
  float* B0    = wsf + 15000000;           //   320,000  [2000][160]
  float* BIAS0 = wsf + 15320000;           //       160
  float* WL    = wsf + 15320160;           //     9,600  3x[20][160]
  float* BIASL = wsf + 15329760;           //       480
  float* BN    = wsf + 15330240;           //       320  4x{sum20,sq20,mu20,rs20}
  int*   ib    = (int*)(wsf + 15330560);
  int* DEG  = ib;                          // 100,000  [2][N]
  int* RP0  = ib + 100000;                 //  50,004
  int* RP1  = ib + 150004;                 //  50,004
  int* NX0  = ib + 200008;                 //  50,000
  int* NX1  = ib + 250008;                 //  50,000
  int* ADJ0 = ib + 300008;                 // 1,600,000
  int* ADJ1 = ib + 1900008;                // 1,600,000

  // pack weights + zero accumulators/degrees
  pack_kernel<<<(430560 + 255)/256, 256, 0, stream>>>(
      W0q, W0k, W0v, W0s, b0q, b0k, b0v, b0s,
      Wq, Wk, Wv, Ws_, bq, bk, bv, bs_,
      B0, BIAS0, WL, BIASL, BN, DEG);

  // CSR by dst, per edge type (indices identical across layers)
  hist_kernel<<<(2*E_EDGES + 255)/256, 256, 0, stream>>>(same, diff, DEG);
  scan_kernel<<<2, 1024, 0, stream>>>(DEG, RP0, RP1, NX0, NX1);
  scatter_kernel<<<(2*E_EDGES + 255)/256, 256, 0, stream>>>(same, diff, NX0, NX1, ADJ0, ADJ1);

  for (int l = 0; l < 4; l++) {
    if (l == 0)
      gemm0_kernel<<<(N_NODES + 63)/64, 256, 0, stream>>>(feat, B0, BIAS0, PROJ);
    else
      proj_small_kernel<<<(N_NODES + 15)/16, 256, 0, stream>>>(
          FCS + (size_t)(l-1)*N_NODES*D, WL + (size_t)(l-1)*3200, BIASL + (size_t)(l-1)*160, PROJ);

    attn_kernel<<<(N_NODES + 3)/4, 256, 0, stream>>>(RP0, ADJ0, PROJ, 0, A0);
    attn_kernel<<<(N_NODES + 3)/4, 256, 0, stream>>>(RP1, ADJ1, PROJ, 1, A1);

    combine_kernel<<<(N_NODES*D + 255)/256, 256, 0, stream>>>(A0, A1, w1, w2, l, XPRE, BN + l*80);
    stats_kernel<<<1, 64, 0, stream>>>(BN + l*80);
    bnapply_kernel<<<(N_NODES*D + 255)/256, 256, 0, stream>>>(
        XPRE, BN + l*80, gamma, beta, l, FCS + (size_t)l*N_NODES*D);
  }

  final_kernel<<<(N_NODES + 255)/256, 256, 0, stream>>>(FCS, Wout, bout, (float*)d_out);
}

// Round 2
// 1483.018 us; speedup vs baseline: 1.6330x; 1.6330x over previous
//
#include <hip/hip_runtime.h>
#include <math.h>

#define N_NODES 50000
#define E_EDGES 1600000
#define F_IN    2000
#define D       20
#define NCOL    160   // 2 edge types * 4 matrices (q,k,v,s) * 20
#define KPAD    2016  // 63 * 32

#define INV_SQRT_D 0.22360679774997896f

typedef __bf16 bf16x8 __attribute__((ext_vector_type(8)));
typedef float  f32x4  __attribute__((ext_vector_type(4)));

// ---------------- pack weights + zero accumulators --------------------------------------
// B0 packed transposed bf16: [160 cols][2016 k], zero-padded k>=2000
__global__ void pack_kernel(
    const float* __restrict__ W0q, const float* __restrict__ W0k,
    const float* __restrict__ W0v, const float* __restrict__ W0s,
    const float* __restrict__ b0q, const float* __restrict__ b0k,
    const float* __restrict__ b0v, const float* __restrict__ b0s,
    const float* __restrict__ Wq,  const float* __restrict__ Wk,
    const float* __restrict__ Wv,  const float* __restrict__ Ws_,
    const float* __restrict__ bq,  const float* __restrict__ bk,
    const float* __restrict__ bv,  const float* __restrict__ bs_,
    __bf16* __restrict__ B0, float* __restrict__ bias0,
    float* __restrict__ WL, float* __restrict__ biasL,
    float* __restrict__ bn, int* __restrict__ deg)
{
  long idx = (long)blockIdx.x * blockDim.x + threadIdx.x;
  if (idx < (long)NCOL*KPAD) {              // B0T: [160][2016] bf16
    int col = (int)(idx / KPAD), k = (int)(idx % KPAD);
    int et = col / 80, r = col % 80, mat = r / 20, d = r % 20;
    const float* w = (mat==0)?W0q:(mat==1)?W0k:(mat==2)?W0v:W0s;
    float v = (k < F_IN) ? w[((size_t)et*F_IN + k)*D + d] : 0.f;
    B0[idx] = (__bf16)v;
    return;
  }
  idx -= (long)NCOL*KPAD;
  if (idx < 160) {                          // bias0
    int col = (int)idx;
    int et = col / 80, r = col % 80, mat = r / 20, d = r % 20;
    const float* b = (mat==0)?b0q:(mat==1)?b0k:(mat==2)?b0v:b0s;
    bias0[col] = b[et*D + d];
    return;
  }
  idx -= 160;
  if (idx < 9600) {                         // WL: 3 x [20][160]
    int l = (int)(idx / 3200), rem = (int)(idx % 3200);
    int k = rem / NCOL, col = rem % NCOL;
    int et = col / 80, r = col % 80, mat = r / 20, d = r % 20;
    const float* w = (mat==0)?Wq:(mat==1)?Wk:(mat==2)?Wv:Ws_;
    WL[idx] = w[(((size_t)l*2 + et)*D + k)*D + d];
    return;
  }
  idx -= 9600;
  if (idx < 480) {                          // biasL: 3 x [160]
    int l = (int)(idx / NCOL), col = (int)(idx % NCOL);
    int et = col / 80, r = col % 80, mat = r / 20, d = r % 20;
    const float* b = (mat==0)?bq:(mat==1)?bk:(mat==2)?bv:bs_;
    biasL[idx] = b[(l*2 + et)*D + d];
    return;
  }
  idx -= 480;
  if (idx < 320) { bn[idx] = 0.f; return; } // BN accumulators, 4 layers x 80
  idx -= 320;
  if (idx < 2*N_NODES) { deg[idx] = 0; return; }
}

// ---------------- CSR build (indices static across layers -> build once per call) -------
__global__ void hist_kernel(const int* __restrict__ same, const int* __restrict__ diff,
                            int* __restrict__ deg)
{
  long i = (long)blockIdx.x * blockDim.x + threadIdx.x;
  if (i >= 2L*E_EDGES) return;
  int et = (i >= E_EDGES) ? 1 : 0;
  long e = i - (long)et*E_EDGES;
  const int* ix = et ? diff : same;
  int dst = ix[E_EDGES + e];
  atomicAdd(&deg[(size_t)et*N_NODES + dst], 1);
}

__global__ void scan_kernel(const int* __restrict__ deg,
                            int* __restrict__ rowptr0, int* __restrict__ rowptr1,
                            int* __restrict__ next0, int* __restrict__ next1)
{
  const int et = blockIdx.x;
  const int* dg = deg + (size_t)et*N_NODES;
  int* rp = et ? rowptr1 : rowptr0;
  int* np = et ? next1 : next0;
  __shared__ int part[1024];
  const int t = threadIdx.x;
  const int per = (N_NODES + 1023) / 1024;  // 49
  const int b = t * per;
  const int e = (b + per < N_NODES) ? (b + per) : N_NODES;
  int s = 0;
  for (int i = b; i < e; i++) s += dg[i];
  part[t] = s;
  __syncthreads();
  for (int o = 1; o < 1024; o <<= 1) {
    int v = (t >= o) ? part[t-o] : 0;
    __syncthreads();
    part[t] += v;
    __syncthreads();
  }
  int run = (t == 0) ? 0 : part[t-1];
  for (int i = b; i < e; i++) {
    rp[i] = run; np[i] = run;
    run += dg[i];
  }
  if (t == 0) rp[N_NODES] = part[1023];
}

__global__ void scatter_kernel(const int* __restrict__ same, const int* __restrict__ diff,
                               int* __restrict__ next0, int* __restrict__ next1,
                               int* __restrict__ adj0, int* __restrict__ adj1)
{
  long i = (long)blockIdx.x * blockDim.x + threadIdx.x;
  if (i >= 2L*E_EDGES) return;
  int et = (i >= E_EDGES) ? 1 : 0;
  long e = i - (long)et*E_EDGES;
  const int* ix = et ? diff : same;
  int src = ix[e];
  int dst = ix[E_EDGES + e];
  int* np  = et ? next1 : next0;
  int* adj = et ? adj1  : adj0;
  int pos = atomicAdd(&np[dst], 1);
  adj[pos] = src;
}

// ---------------- layer-0 MFMA GEMM: [50000,2000]fp32 -> bf16 @ [2016,160]bf16 ----------
// 8 waves: 4x2 wave grid, each wave 32 rows x 80 cols (2x5 16x16 frags).
// A staged fp32->bf16 in LDS (reg prefetch); B frags direct from L2 (640KB resident).
__launch_bounds__(512)
__global__ void gemm0_mfma(const float* __restrict__ A,
                           const __bf16* __restrict__ Bt,
                           const float* __restrict__ bias,
                           float* __restrict__ C)
{
  __shared__ __bf16 as[128*32];
  const int t    = threadIdx.x;
  const int lane = t & 63;
  const int wid  = t >> 6;
  const int wr   = wid >> 1;        // 0..3 -> rows wr*32
  const int wc   = wid & 1;         // 0..1 -> cols wc*80
  const int rb0  = blockIdx.x * 128;

  const int srow = t >> 2;          // staging: row 0..127
  const int skc  = (t & 3) * 8;     // k chunk of 8
  const int arow = rb0 + srow;
  const float* aptr = A + (size_t)arow * F_IN;

  const int lrow = lane & 15;       // frag row/col within 16
  const int lkb  = (lane >> 4) * 8; // k sub-block

  f32x4 acc[2][5];
#pragma unroll
  for (int i = 0; i < 2; i++)
#pragma unroll
    for (int j = 0; j < 5; j++) acc[i][j] = (f32x4){0.f,0.f,0.f,0.f};

  float4 p0, p1;
  auto loadA = [&](int k0) {
    int k = k0 + skc;
    if (arow < N_NODES) {
      if (k + 8 <= F_IN) {
        p0 = *(const float4*)(aptr + k);
        p1 = *(const float4*)(aptr + k + 4);
      } else {
        float tmp[8];
#pragma unroll
        for (int i = 0; i < 8; i++) tmp[i] = (k + i < F_IN) ? aptr[k + i] : 0.f;
        p0 = make_float4(tmp[0],tmp[1],tmp[2],tmp[3]);
        p1 = make_float4(tmp[4],tmp[5],tmp[6],tmp[7]);
      }
    } else {
      p0 = make_float4(0,0,0,0); p1 = p0;
    }
  };

  loadA(0);
  for (int s = 0; s < 63; s++) {
    bf16x8 h;
    h[0]=(__bf16)p0.x; h[1]=(__bf16)p0.y; h[2]=(__bf16)p0.z; h[3]=(__bf16)p0.w;
    h[4]=(__bf16)p1.x; h[5]=(__bf16)p1.y; h[6]=(__bf16)p1.z; h[7]=(__bf16)p1.w;
    *(bf16x8*)&as[srow*32 + skc] = h;
    __syncthreads();
    if (s + 1 < 63) loadA((s + 1) * 32);

    bf16x8 af[2];
#pragma unroll
    for (int rf = 0; rf < 2; rf++)
      af[rf] = *(bf16x8*)&as[(wr*32 + rf*16 + lrow)*32 + lkb];
    bf16x8 bfr[5];
#pragma unroll
    for (int cf = 0; cf < 5; cf++)
      bfr[cf] = *(const bf16x8*)(Bt + (size_t)(wc*80 + cf*16 + lrow)*KPAD + s*32 + lkb);
#pragma unroll
    for (int rf = 0; rf < 2; rf++)
#pragma unroll
      for (int cf = 0; cf < 5; cf++)
        acc[rf][cf] = __builtin_amdgcn_mfma_f32_16x16x32_bf16(af[rf], bfr[cf], acc[rf][cf], 0, 0, 0);
    __syncthreads();
  }

  // epilogue: C/D layout col=lane&15, row=(lane>>4)*4 + j
#pragma unroll
  for (int rf = 0; rf < 2; rf++) {
#pragma unroll
    for (int cf = 0; cf < 5; cf++) {
      int col = wc*80 + cf*16 + lrow;
      float bv = bias[col];
#pragma unroll
      for (int j = 0; j < 4; j++) {
        int r = rb0 + wr*32 + rf*16 + (lane >> 4)*4 + j;
        if (r < N_NODES) C[(size_t)r*NCOL + col] = acc[rf][cf][j] + bv;
      }
    }
  }
}

// ---------------- layers 1..3 projection: [N,20] @ [20,160] + bias ----------------------
__launch_bounds__(256)
__global__ void proj_small_kernel(const float* __restrict__ x, const float* __restrict__ W,
                                  const float* __restrict__ bias, float* __restrict__ C)
{
  __shared__ float ws[20*160];
  __shared__ float xs[16*20];
  const int t = threadIdx.x;
  const int n0 = blockIdx.x * 16;
#pragma unroll
  for (int i = 0; i < 13; i++) {
    int idx = t + i*256;
    if (idx < 3200) ws[idx] = W[idx];
  }
#pragma unroll
  for (int i = 0; i < 2; i++) {
    int idx = t + i*256;
    if (idx < 320) {
      int nl = idx / 20, k = idx % 20;
      int n = n0 + nl;
      xs[idx] = (n < N_NODES) ? x[(size_t)n*D + k] : 0.f;
    }
  }
  __syncthreads();
#pragma unroll
  for (int i = 0; i < 10; i++) {
    int idx = t + i*256;
    int nl = idx / NCOL, col = idx % NCOL;
    int n = n0 + nl;
    if (n < N_NODES) {
      float acc = bias[col];
#pragma unroll
      for (int k = 0; k < 20; k++) acc += xs[nl*20 + k] * ws[k*NCOL + col];
      C[(size_t)n*NCOL + col] = acc;
    }
  }
}

// ---------------- gather attention: 16 lanes per dst node, online softmax ---------------
__launch_bounds__(256)
__global__ void attn_kernel(const int* __restrict__ rowptr0, const int* __restrict__ adj0,
                            const int* __restrict__ rowptr1, const int* __restrict__ adj1,
                            const float* __restrict__ proj,
                            float* __restrict__ out0, float* __restrict__ out1)
{
  const int et   = blockIdx.y;
  const int* rowptr = et ? rowptr1 : rowptr0;
  const int* adj    = et ? adj1 : adj0;
  float* xout       = et ? out1 : out0;

  const int t    = threadIdx.x;
  const int node = blockIdx.x*16 + (t >> 4);
  const int sl   = t & 15;
  if (node >= N_NODES) return;

  const size_t rowb = (size_t)node*NCOL + (size_t)et*80;
  float4 qv[5];
#pragma unroll
  for (int j = 0; j < 5; j++) qv[j] = *(const float4*)(proj + rowb + 4*j);

  const int beg = rowptr[node], end = rowptr[node+1];

  float m = -INFINITY, z = 0.f;
  float S[20];
#pragma unroll
  for (int d = 0; d < 20; d++) S[d] = 0.f;

  for (int i = beg + sl; i < end; i += 16) {
    const int src = adj[i];
    const float* kp = proj + (size_t)src*NCOL + (size_t)et*80 + 20;  // k then v (40 floats)
    float4 kv[5], vv[5];
#pragma unroll
    for (int j = 0; j < 5; j++) kv[j] = *(const float4*)(kp + 4*j);
#pragma unroll
    for (int j = 0; j < 5; j++) vv[j] = *(const float4*)(kp + 20 + 4*j);
    float dot = 0.f;
#pragma unroll
    for (int j = 0; j < 5; j++)
      dot += qv[j].x*kv[j].x + qv[j].y*kv[j].y + qv[j].z*kv[j].z + qv[j].w*kv[j].w;
    dot *= INV_SQRT_D;
    float nm = fmaxf(m, dot);
    float a  = __expf(m - nm);     // m=-inf first iter -> 0
    float w  = __expf(dot - nm);
    z = z*a + w;
#pragma unroll
    for (int j = 0; j < 5; j++) {
      S[4*j+0] = S[4*j+0]*a + w*vv[j].x;
      S[4*j+1] = S[4*j+1]*a + w*vv[j].y;
      S[4*j+2] = S[4*j+2]*a + w*vv[j].z;
      S[4*j+3] = S[4*j+3]*a + w*vv[j].w;
    }
    m = nm;
  }

  // merge 16 lanes (online-softmax butterfly); fminf guards -inf - -inf = NaN
#pragma unroll
  for (int o = 8; o >= 1; o >>= 1) {
    float m2 = __shfl_xor(m, o, 64);
    float z2 = __shfl_xor(z, o, 64);
    float nm = fmaxf(m, m2);
    float a  = __expf(fminf(m  - nm, 0.f));
    float b  = __expf(fminf(m2 - nm, 0.f));
    z = z*a + z2*b;
#pragma unroll
    for (int d = 0; d < 20; d++) {
      float s2 = __shfl_xor(S[d], o, 64);
      S[d] = S[d]*a + s2*b;
    }
    m = nm;
  }

  if (sl == 0) {
    const float inv = 1.f / (z + 1e-16f);
    const float* sp = proj + rowb + 60;   // skip term x@Ws+bs
    float* xo = xout + (size_t)node*D;
#pragma unroll
    for (int j = 0; j < 5; j++) {
      float4 sv = *(const float4*)(sp + 4*j);
      float4 o4;
      o4.x = S[4*j+0]*inv + sv.x;
      o4.y = S[4*j+1]*inv + sv.y;
      o4.z = S[4*j+2]*inv + sv.z;
      o4.w = S[4*j+3]*inv + sv.w;
      *(float4*)(xo + 4*j) = o4;
    }
  }
}

// ---------------- combine edge types + BN partial sums ----------------------------------
__global__ void combine_kernel(const float* __restrict__ A0, const float* __restrict__ A1,
                               const float* __restrict__ w1, const float* __restrict__ w2,
                               int l, float* __restrict__ xpre, float* __restrict__ bn)
{
  __shared__ float ls[40];
  const int t = threadIdx.x;
  if (t < 40) ls[t] = 0.f;
  __syncthreads();
  const int i = blockIdx.x*256 + t;
  if (i < N_NODES*D) {
    float a = w1[l], b = w2[l];
    float tt = a + b;
    float v = (a/tt)*A0[i] + (b/tt)*A1[i];
    xpre[i] = v;
    int d = i % D;
    atomicAdd(&ls[d], v);
    atomicAdd(&ls[20+d], v*v);
  }
  __syncthreads();
  if (t < 40) atomicAdd(&bn[t], ls[t]);
}

__global__ void stats_kernel(float* __restrict__ bn)
{
  int t = threadIdx.x;
  if (t < D) {
    float mu  = bn[t] * (1.f/N_NODES);
    float var = bn[20+t] * (1.f/N_NODES) - mu*mu;
    bn[40+t] = mu;
    bn[60+t] = 1.f / sqrtf(var + 1e-5f);
  }
}

__global__ void bnapply_kernel(const float* __restrict__ xpre, const float* __restrict__ bn,
                               const float* __restrict__ gamma, const float* __restrict__ beta,
                               int l, float* __restrict__ out)
{
  const int i = blockIdx.x*256 + threadIdx.x;
  if (i >= N_NODES*D) return;
  const int d = i % D;
  float v = (xpre[i] - bn[40+d]) * bn[60+d] * gamma[l*D+d] + beta[l*D+d];
  out[i] = (v > 0.f) ? v : 0.01f*v;
}

// ---------------- final: concat(fcs) @ Wout + bout --------------------------------------
__global__ void final_kernel(const float* __restrict__ fcs, const float* __restrict__ Wout,
                             const float* __restrict__ bout, float* __restrict__ out)
{
  const int n = blockIdx.x*256 + threadIdx.x;
  if (n >= N_NODES) return;
  float a0 = bout[0], a1 = bout[1];
#pragma unroll
  for (int l = 0; l < 4; l++) {
    const float* base = fcs + (size_t)l*N_NODES*D + (size_t)n*D;
#pragma unroll
    for (int d = 0; d < D; d++) {
      float v = base[d];
      a0 += v * Wout[(l*D+d)*2 + 0];
      a1 += v * Wout[(l*D+d)*2 + 1];
    }
  }
  out[n*2+0] = a0;
  out[n*2+1] = a1;
}

// ----------------------------------------------------------------------------------------
extern "C" void kernel_launch(void* const* d_in, const int* in_sizes, int n_in,
                              void* d_out, int out_size, void* d_ws, size_t ws_size,
                              hipStream_t stream)
{
  const float* feat = (const float*)d_in[0];
  const int*   same = (const int*)d_in[1];
  const int*   diff = (const int*)d_in[2];
  const float* W0q = (const float*)d_in[3];
  const float* b0q = (const float*)d_in[4];
  const float* W0k = (const float*)d_in[5];
  const float* b0k = (const float*)d_in[6];
  const float* W0v = (const float*)d_in[7];
  const float* b0v = (const float*)d_in[8];
  const float* W0s = (const float*)d_in[9];
  const float* b0s = (const float*)d_in[10];
  const float* Wq  = (const float*)d_in[11];
  const float* bq  = (const float*)d_in[12];
  const float* Wk  = (const float*)d_in[13];
  const float* bk  = (const float*)d_in[14];
  const float* Wv  = (const float*)d_in[15];
  const float* bv  = (const float*)d_in[16];
  const float* Ws_ = (const float*)d_in[17];
  const float* bs_ = (const float*)d_in[18];
  const float* w1  = (const float*)d_in[19];
  const float* w2  = (const float*)d_in[20];
  const float* gamma = (const float*)d_in[21];
  const float* beta  = (const float*)d_in[22];
  const float* Wout  = (const float*)d_in[23];
  const float* bout  = (const float*)d_in[24];

  float* wsf  = (float*)d_ws;
  float*   PROJ  = wsf;                      // 8,000,000  [N][160]
  float*   A0    = wsf + 8000000;            // 1,000,000  [N][20]
  float*   A1    = wsf + 9000000;            // 1,000,000
  float*   XPRE  = wsf + 10000000;           // 1,000,000
  float*   FCS   = wsf + 11000000;           // 4,000,000  [4][N][20]
  __bf16*  B0bf  = (__bf16*)(wsf + 15000000);//   322,560 bf16 = 161,280 floats
  float*   BIAS0 = wsf + 15161280;           //       160
  float*   WL    = wsf + 15161440;           //     9,600  3x[20][160]
  float*   BIASL = wsf + 15171040;           //       480
  float*   BN    = wsf + 15171520;           //       320  4x{sum20,sq20,mu20,rs20}
  int*     ib    = (int*)(wsf + 15171840);
  int* DEG  = ib;                            // 100,000  [2][N]
  int* RP0  = ib + 100000;                   //  50,004
  int* RP1  = ib + 150004;                   //  50,004
  int* NX0  = ib + 200008;                   //  50,000
  int* NX1  = ib + 250008;                   //  50,000
  int* ADJ0 = ib + 300008;                   // 1,600,000
  int* ADJ1 = ib + 1900008;                  // 1,600,000

  // pack weights + zero accumulators/degrees
  const int packN = NCOL*KPAD + 160 + 9600 + 480 + 320 + 2*N_NODES;  // 433,120
  pack_kernel<<<(packN + 255)/256, 256, 0, stream>>>(
      W0q, W0k, W0v, W0s, b0q, b0k, b0v, b0s,
      Wq, Wk, Wv, Ws_, bq, bk, bv, bs_,
      B0bf, BIAS0, WL, BIASL, BN, DEG);

  // CSR by dst, per edge type (indices identical across layers)
  hist_kernel<<<(2*E_EDGES + 255)/256, 256, 0, stream>>>(same, diff, DEG);
  scan_kernel<<<2, 1024, 0, stream>>>(DEG, RP0, RP1, NX0, NX1);
  scatter_kernel<<<(2*E_EDGES + 255)/256, 256, 0, stream>>>(same, diff, NX0, NX1, ADJ0, ADJ1);

  dim3 attn_grid((N_NODES + 15)/16, 2);

  for (int l = 0; l < 4; l++) {
    if (l == 0)
      gemm0_mfma<<<(N_NODES + 127)/128, 512, 0, stream>>>(feat, B0bf, BIAS0, PROJ);
    else
      proj_small_kernel<<<(N_NODES + 15)/16, 256, 0, stream>>>(
          FCS + (size_t)(l-1)*N_NODES*D, WL + (size_t)(l-1)*3200, BIASL + (size_t)(l-1)*160, PROJ);

    attn_kernel<<<attn_grid, 256, 0, stream>>>(RP0, ADJ0, RP1, ADJ1, PROJ, A0, A1);

    combine_kernel<<<(N_NODES*D + 255)/256, 256, 0, stream>>>(A0, A1, w1, w2, l, XPRE, BN + l*80);
    stats_kernel<<<1, 64, 0, stream>>>(BN + l*80);
    bnapply_kernel<<<(N_NODES*D + 255)/256, 256, 0, stream>>>(
        XPRE, BN + l*80, gamma, beta, l, FCS + (size_t)l*N_NODES*D);
  }

  final_kernel<<<(N_NODES + 255)/256, 256, 0, stream>>>(FCS, Wout, bout, (float*)d_out);
}

// Round 3
// 1172.970 us; speedup vs baseline: 2.0646x; 1.2643x over previous
//
#include <hip/hip_runtime.h>
#include <math.h>

#define N_NODES 50000
#define E_EDGES 1600000
#define F_IN    2000
#define D       20
#define NCOL    160   // 2 edge types * [q s k v] * 20  (col order: q,s,k,v per edge type)
#define KPAD    2016  // 63 * 32

#define INV_SQRT_D 0.22360679774997896f

typedef __bf16 bf16x8 __attribute__((ext_vector_type(8)));
typedef __bf16 bf16x4 __attribute__((ext_vector_type(4)));
typedef float  f32x4  __attribute__((ext_vector_type(4)));

// ---------------- pack weights + zero accumulators --------------------------------------
// Column order within each 80-col edge-type block: q(0-19) s(20-39) k(40-59) v(60-79)
// -> attention gathers k+v as one 80B 16B-aligned chunk.
__global__ void pack_kernel(
    const float* __restrict__ W0q, const float* __restrict__ W0k,
    const float* __restrict__ W0v, const float* __restrict__ W0s,
    const float* __restrict__ b0q, const float* __restrict__ b0k,
    const float* __restrict__ b0v, const float* __restrict__ b0s,
    const float* __restrict__ Wq,  const float* __restrict__ Wk,
    const float* __restrict__ Wv,  const float* __restrict__ Ws_,
    const float* __restrict__ bq,  const float* __restrict__ bk,
    const float* __restrict__ bv,  const float* __restrict__ bs_,
    __bf16* __restrict__ B0, float* __restrict__ bias0,
    float* __restrict__ WL, float* __restrict__ biasL,
    float* __restrict__ bn, int* __restrict__ deg)
{
  long idx = (long)blockIdx.x * blockDim.x + threadIdx.x;
  if (idx < (long)NCOL*KPAD) {              // B0T: [160][2016] bf16
    int col = (int)(idx / KPAD), k = (int)(idx % KPAD);
    int et = col / 80, r = col % 80, mat = r / 20, d = r % 20;
    const float* w = (mat==0)?W0q:(mat==1)?W0s:(mat==2)?W0k:W0v;
    float v = (k < F_IN) ? w[((size_t)et*F_IN + k)*D + d] : 0.f;
    B0[idx] = (__bf16)v;
    return;
  }
  idx -= (long)NCOL*KPAD;
  if (idx < 160) {                          // bias0
    int col = (int)idx;
    int et = col / 80, r = col % 80, mat = r / 20, d = r % 20;
    const float* b = (mat==0)?b0q:(mat==1)?b0s:(mat==2)?b0k:b0v;
    bias0[col] = b[et*D + d];
    return;
  }
  idx -= 160;
  if (idx < 9600) {                         // WL: 3 x [20][160]
    int l = (int)(idx / 3200), rem = (int)(idx % 3200);
    int k = rem / NCOL, col = rem % NCOL;
    int et = col / 80, r = col % 80, mat = r / 20, d = r % 20;
    const float* w = (mat==0)?Wq:(mat==1)?Ws_:(mat==2)?Wk:Wv;
    WL[idx] = w[(((size_t)l*2 + et)*D + k)*D + d];
    return;
  }
  idx -= 9600;
  if (idx < 480) {                          // biasL: 3 x [160]
    int l = (int)(idx / NCOL), col = (int)(idx % NCOL);
    int et = col / 80, r = col % 80, mat = r / 20, d = r % 20;
    const float* b = (mat==0)?bq:(mat==1)?bs_:(mat==2)?bk:bv;
    biasL[idx] = b[(l*2 + et)*D + d];
    return;
  }
  idx -= 480;
  if (idx < 320) { bn[idx] = 0.f; return; } // BN accumulators, 4 layers x 80
  idx -= 320;
  if (idx < 2*N_NODES) { deg[idx] = 0; return; }
}

// ---------------- CSR build (indices static across layers -> build once per call) -------
__global__ void hist_kernel(const int* __restrict__ same, const int* __restrict__ diff,
                            int* __restrict__ deg)
{
  long i = (long)blockIdx.x * blockDim.x + threadIdx.x;
  if (i >= 2L*E_EDGES) return;
  int et = (i >= E_EDGES) ? 1 : 0;
  long e = i - (long)et*E_EDGES;
  const int* ix = et ? diff : same;
  int dst = ix[E_EDGES + e];
  atomicAdd(&deg[(size_t)et*N_NODES + dst], 1);
}

__global__ void scan_kernel(const int* __restrict__ deg,
                            int* __restrict__ rowptr0, int* __restrict__ rowptr1,
                            int* __restrict__ next0, int* __restrict__ next1)
{
  const int et = blockIdx.x;
  const int* dg = deg + (size_t)et*N_NODES;
  int* rp = et ? rowptr1 : rowptr0;
  int* np = et ? next1 : next0;
  __shared__ int part[1024];
  const int t = threadIdx.x;
  const int per = (N_NODES + 1023) / 1024;  // 49
  const int b = t * per;
  const int e = (b + per < N_NODES) ? (b + per) : N_NODES;
  int s = 0;
  for (int i = b; i < e; i++) s += dg[i];
  part[t] = s;
  __syncthreads();
  for (int o = 1; o < 1024; o <<= 1) {
    int v = (t >= o) ? part[t-o] : 0;
    __syncthreads();
    part[t] += v;
    __syncthreads();
  }
  int run = (t == 0) ? 0 : part[t-1];
  for (int i = b; i < e; i++) {
    rp[i] = run; np[i] = run;
    run += dg[i];
  }
  if (t == 0) rp[N_NODES] = part[1023];
}

// XCD-partitioned scatter: partition p (= blockIdx&7, default round-robin XCD mapping)
// owns dst range [p*6250,(p+1)*6250) so each adj cache line is dirtied from one XCD.
#define SC_EPT 16
#define SC_CHUNK (256*SC_EPT)
__global__ void scatter_kernel(const int* __restrict__ same, const int* __restrict__ diff,
                               int* __restrict__ next0, int* __restrict__ next1,
                               int* __restrict__ adj0, int* __restrict__ adj1)
{
  const int part  = blockIdx.x & 7;
  const int chunk = blockIdx.x >> 3;
  const int lo = part * (N_NODES/8);
  const int hi = lo + (N_NODES/8);
  const long i0 = (long)chunk * SC_CHUNK + threadIdx.x;
#pragma unroll
  for (int it = 0; it < SC_EPT; ++it) {
    long i = i0 + (long)it*256;
    if (i >= 2L*E_EDGES) break;
    int et = (i >= E_EDGES) ? 1 : 0;
    long e = i - (long)et*E_EDGES;
    const int* ix = et ? diff : same;
    int dst = ix[E_EDGES + e];
    if (dst >= lo && dst < hi) {
      int src = ix[e];
      int* np  = et ? next1 : next0;
      int* adj = et ? adj1  : adj0;
      int pos = atomicAdd(&np[dst], 1);
      adj[pos] = src;
    }
  }
}

// ---------------- layer-0 MFMA GEMM: [50000,2000]fp32 -> bf16 @ [2016,160]bf16 ----------
__launch_bounds__(512)
__global__ void gemm0_mfma(const float* __restrict__ A,
                           const __bf16* __restrict__ Bt,
                           const float* __restrict__ bias,
                           __bf16* __restrict__ C)
{
  __shared__ __bf16 as[128*32];
  const int t    = threadIdx.x;
  const int lane = t & 63;
  const int wid  = t >> 6;
  const int wr   = wid >> 1;        // 0..3 -> rows wr*32
  const int wc   = wid & 1;         // 0..1 -> cols wc*80
  const int rb0  = blockIdx.x * 128;

  const int srow = t >> 2;          // staging: row 0..127
  const int skc  = (t & 3) * 8;     // k chunk of 8
  const int arow = rb0 + srow;
  const float* aptr = A + (size_t)arow * F_IN;

  const int lrow = lane & 15;       // frag row/col within 16
  const int lkb  = (lane >> 4) * 8; // k sub-block

  f32x4 acc[2][5];
#pragma unroll
  for (int i = 0; i < 2; i++)
#pragma unroll
    for (int j = 0; j < 5; j++) acc[i][j] = (f32x4){0.f,0.f,0.f,0.f};

  float4 p0, p1;
  auto loadA = [&](int k0) {
    int k = k0 + skc;
    if (arow < N_NODES) {
      if (k + 8 <= F_IN) {
        p0 = *(const float4*)(aptr + k);
        p1 = *(const float4*)(aptr + k + 4);
      } else {
        float tmp[8];
#pragma unroll
        for (int i = 0; i < 8; i++) tmp[i] = (k + i < F_IN) ? aptr[k + i] : 0.f;
        p0 = make_float4(tmp[0],tmp[1],tmp[2],tmp[3]);
        p1 = make_float4(tmp[4],tmp[5],tmp[6],tmp[7]);
      }
    } else {
      p0 = make_float4(0,0,0,0); p1 = p0;
    }
  };

  loadA(0);
  for (int s = 0; s < 63; s++) {
    bf16x8 h;
    h[0]=(__bf16)p0.x; h[1]=(__bf16)p0.y; h[2]=(__bf16)p0.z; h[3]=(__bf16)p0.w;
    h[4]=(__bf16)p1.x; h[5]=(__bf16)p1.y; h[6]=(__bf16)p1.z; h[7]=(__bf16)p1.w;
    *(bf16x8*)&as[srow*32 + skc] = h;
    __syncthreads();
    if (s + 1 < 63) loadA((s + 1) * 32);

    bf16x8 af[2];
#pragma unroll
    for (int rf = 0; rf < 2; rf++)
      af[rf] = *(bf16x8*)&as[(wr*32 + rf*16 + lrow)*32 + lkb];
    bf16x8 bfr[5];
#pragma unroll
    for (int cf = 0; cf < 5; cf++)
      bfr[cf] = *(const bf16x8*)(Bt + (size_t)(wc*80 + cf*16 + lrow)*KPAD + s*32 + lkb);
#pragma unroll
    for (int rf = 0; rf < 2; rf++)
#pragma unroll
      for (int cf = 0; cf < 5; cf++)
        acc[rf][cf] = __builtin_amdgcn_mfma_f32_16x16x32_bf16(af[rf], bfr[cf], acc[rf][cf], 0, 0, 0);
    __syncthreads();
  }

  // epilogue: C/D layout col=lane&15, row=(lane>>4)*4 + j ; C is bf16 [N][160]
#pragma unroll
  for (int rf = 0; rf < 2; rf++) {
#pragma unroll
    for (int cf = 0; cf < 5; cf++) {
      int col = wc*80 + cf*16 + lrow;
      float bv = bias[col];
#pragma unroll
      for (int j = 0; j < 4; j++) {
        int r = rb0 + wr*32 + rf*16 + (lane >> 4)*4 + j;
        if (r < N_NODES) C[(size_t)r*NCOL + col] = (__bf16)(acc[rf][cf][j] + bv);
      }
    }
  }
}

// ---------------- layers 1..3 projection: [N,20]fp32 @ [20,160]fp32 -> bf16 -------------
__launch_bounds__(256)
__global__ void proj_small_kernel(const float* __restrict__ x, const float* __restrict__ W,
                                  const float* __restrict__ bias, __bf16* __restrict__ C)
{
  __shared__ float ws[20*160];
  __shared__ float xs[16*20];
  const int t = threadIdx.x;
  const int n0 = blockIdx.x * 16;
#pragma unroll
  for (int i = 0; i < 13; i++) {
    int idx = t + i*256;
    if (idx < 3200) ws[idx] = W[idx];
  }
#pragma unroll
  for (int i = 0; i < 2; i++) {
    int idx = t + i*256;
    if (idx < 320) {
      int nl = idx / 20, k = idx % 20;
      int n = n0 + nl;
      xs[idx] = (n < N_NODES) ? x[(size_t)n*D + k] : 0.f;
    }
  }
  __syncthreads();
#pragma unroll
  for (int i = 0; i < 10; i++) {
    int idx = t + i*256;
    int nl = idx / NCOL, col = idx % NCOL;
    int n = n0 + nl;
    if (n < N_NODES) {
      float acc = bias[col];
#pragma unroll
      for (int k = 0; k < 20; k++) acc += xs[nl*20 + k] * ws[k*NCOL + col];
      C[(size_t)n*NCOL + col] = (__bf16)acc;
    }
  }
}

// ---------------- gather attention: 16 lanes per dst node, online softmax, bf16 PROJ ----
__launch_bounds__(256)
__global__ void attn_kernel(const int* __restrict__ rowptr0, const int* __restrict__ adj0,
                            const int* __restrict__ rowptr1, const int* __restrict__ adj1,
                            const __bf16* __restrict__ proj,
                            float* __restrict__ out0, float* __restrict__ out1)
{
  const int et   = blockIdx.y;
  const int* rowptr = et ? rowptr1 : rowptr0;
  const int* adj    = et ? adj1 : adj0;
  float* xout       = et ? out1 : out0;

  const int t    = threadIdx.x;
  const int node = blockIdx.x*16 + (t >> 4);
  const int sl   = t & 15;
  if (node >= N_NODES) return;

  const __bf16* rq = proj + (size_t)node*NCOL + et*80;   // q at +0 (16B aligned)
  float qf[20];
  {
    bf16x8 q0 = *(const bf16x8*)(rq);
    bf16x8 q1 = *(const bf16x8*)(rq + 8);
    bf16x4 q2 = *(const bf16x4*)(rq + 16);
#pragma unroll
    for (int i = 0; i < 8; i++) { qf[i] = (float)q0[i]; qf[8+i] = (float)q1[i]; }
#pragma unroll
    for (int i = 0; i < 4; i++) qf[16+i] = (float)q2[i];
  }

  const int beg = rowptr[node], end = rowptr[node+1];

  float m = -INFINITY, z = 0.f;
  float S[20];
#pragma unroll
  for (int d = 0; d < 20; d++) S[d] = 0.f;

  for (int i = beg + sl; i < end; i += 16) {
    const int src = adj[i];
    // k(20) v(20) contiguous at +40 within the 80-col et block, 16B aligned
    const __bf16* kv = proj + (size_t)src*NCOL + et*80 + 40;
    bf16x8 c0 = *(const bf16x8*)(kv);
    bf16x8 c1 = *(const bf16x8*)(kv + 8);
    bf16x8 c2 = *(const bf16x8*)(kv + 16);
    bf16x8 c3 = *(const bf16x8*)(kv + 24);
    bf16x8 c4 = *(const bf16x8*)(kv + 32);

    float dot = 0.f;
#pragma unroll
    for (int i2 = 0; i2 < 8; i2++) dot += qf[i2]      * (float)c0[i2];
#pragma unroll
    for (int i2 = 0; i2 < 8; i2++) dot += qf[8 + i2]  * (float)c1[i2];
#pragma unroll
    for (int i2 = 0; i2 < 4; i2++) dot += qf[16 + i2] * (float)c2[i2];
    dot *= INV_SQRT_D;

    float nm = fmaxf(m, dot);
    float a  = __expf(m - nm);     // m=-inf first iter -> 0
    float w  = __expf(dot - nm);
    z = z*a + w;
#pragma unroll
    for (int d = 0; d < 4; d++)  S[d]      = S[d]*a      + w*(float)c2[4 + d];
#pragma unroll
    for (int d = 0; d < 8; d++)  S[4 + d]  = S[4 + d]*a  + w*(float)c3[d];
#pragma unroll
    for (int d = 0; d < 8; d++)  S[12 + d] = S[12 + d]*a + w*(float)c4[d];
    m = nm;
  }

  // merge 16 lanes (online-softmax butterfly); fminf guards -inf - -inf = NaN
#pragma unroll
  for (int o = 8; o >= 1; o >>= 1) {
    float m2 = __shfl_xor(m, o, 64);
    float z2 = __shfl_xor(z, o, 64);
    float nm = fmaxf(m, m2);
    float a  = __expf(fminf(m  - nm, 0.f));
    float b  = __expf(fminf(m2 - nm, 0.f));
    z = z*a + z2*b;
#pragma unroll
    for (int d = 0; d < 20; d++) {
      float s2 = __shfl_xor(S[d], o, 64);
      S[d] = S[d]*a + s2*b;
    }
    m = nm;
  }

  if (sl == 0) {
    const float inv = 1.f / (z + 1e-16f);
    const __bf16* sp = rq + 20;           // skip term x@Ws+bs at +20
    float* xo = xout + (size_t)node*D;
    float sv[20];
    {
      bf16x4 s0 = *(const bf16x4*)(sp);
      bf16x8 s1 = *(const bf16x8*)(sp + 4);
      bf16x8 s2 = *(const bf16x8*)(sp + 12);
#pragma unroll
      for (int i = 0; i < 4; i++) sv[i] = (float)s0[i];
#pragma unroll
      for (int i = 0; i < 8; i++) { sv[4+i] = (float)s1[i]; sv[12+i] = (float)s2[i]; }
    }
#pragma unroll
    for (int j = 0; j < 5; j++) {
      float4 o4;
      o4.x = S[4*j+0]*inv + sv[4*j+0];
      o4.y = S[4*j+1]*inv + sv[4*j+1];
      o4.z = S[4*j+2]*inv + sv[4*j+2];
      o4.w = S[4*j+3]*inv + sv[4*j+3];
      *(float4*)(xo + 4*j) = o4;
    }
  }
}

// ---------------- combine edge types + BN partial sums ----------------------------------
__global__ void combine_kernel(const float* __restrict__ A0, const float* __restrict__ A1,
                               const float* __restrict__ w1, const float* __restrict__ w2,
                               int l, float* __restrict__ xpre, float* __restrict__ bn)
{
  __shared__ float ls[40];
  const int t = threadIdx.x;
  if (t < 40) ls[t] = 0.f;
  __syncthreads();
  const int i = blockIdx.x*256 + t;
  if (i < N_NODES*D) {
    float a = w1[l], b = w2[l];
    float tt = a + b;
    float v = (a/tt)*A0[i] + (b/tt)*A1[i];
    xpre[i] = v;
    int d = i % D;
    atomicAdd(&ls[d], v);
    atomicAdd(&ls[20+d], v*v);
  }
  __syncthreads();
  if (t < 40) atomicAdd(&bn[t], ls[t]);
}

__global__ void stats_kernel(float* __restrict__ bn)
{
  int t = threadIdx.x;
  if (t < D) {
    float mu  = bn[t] * (1.f/N_NODES);
    float var = bn[20+t] * (1.f/N_NODES) - mu*mu;
    bn[40+t] = mu;
    bn[60+t] = 1.f / sqrtf(var + 1e-5f);
  }
}

__global__ void bnapply_kernel(const float* __restrict__ xpre, const float* __restrict__ bn,
                               const float* __restrict__ gamma, const float* __restrict__ beta,
                               int l, float* __restrict__ out)
{
  const int i = blockIdx.x*256 + threadIdx.x;
  if (i >= N_NODES*D) return;
  const int d = i % D;
  float v = (xpre[i] - bn[40+d]) * bn[60+d] * gamma[l*D+d] + beta[l*D+d];
  out[i] = (v > 0.f) ? v : 0.01f*v;
}

// ---------------- final: concat(fcs) @ Wout + bout --------------------------------------
__global__ void final_kernel(const float* __restrict__ fcs, const float* __restrict__ Wout,
                             const float* __restrict__ bout, float* __restrict__ out)
{
  const int n = blockIdx.x*256 + threadIdx.x;
  if (n >= N_NODES) return;
  float a0 = bout[0], a1 = bout[1];
#pragma unroll
  for (int l = 0; l < 4; l++) {
    const float* base = fcs + (size_t)l*N_NODES*D + (size_t)n*D;
#pragma unroll
    for (int d = 0; d < D; d++) {
      float v = base[d];
      a0 += v * Wout[(l*D+d)*2 + 0];
      a1 += v * Wout[(l*D+d)*2 + 1];
    }
  }
  out[n*2+0] = a0;
  out[n*2+1] = a1;
}

// ----------------------------------------------------------------------------------------
extern "C" void kernel_launch(void* const* d_in, const int* in_sizes, int n_in,
                              void* d_out, int out_size, void* d_ws, size_t ws_size,
                              hipStream_t stream)
{
  const float* feat = (const float*)d_in[0];
  const int*   same = (const int*)d_in[1];
  const int*   diff = (const int*)d_in[2];
  const float* W0q = (const float*)d_in[3];
  const float* b0q = (const float*)d_in[4];
  const float* W0k = (const float*)d_in[5];
  const float* b0k = (const float*)d_in[6];
  const float* W0v = (const float*)d_in[7];
  const float* b0v = (const float*)d_in[8];
  const float* W0s = (const float*)d_in[9];
  const float* b0s = (const float*)d_in[10];
  const float* Wq  = (const float*)d_in[11];
  const float* bq  = (const float*)d_in[12];
  const float* Wk  = (const float*)d_in[13];
  const float* bk  = (const float*)d_in[14];
  const float* Wv  = (const float*)d_in[15];
  const float* bv  = (const float*)d_in[16];
  const float* Ws_ = (const float*)d_in[17];
  const float* bs_ = (const float*)d_in[18];
  const float* w1  = (const float*)d_in[19];
  const float* w2  = (const float*)d_in[20];
  const float* gamma = (const float*)d_in[21];
  const float* beta  = (const float*)d_in[22];
  const float* Wout  = (const float*)d_in[23];
  const float* bout  = (const float*)d_in[24];

  float* wsf  = (float*)d_ws;
  __bf16*  PROJ  = (__bf16*)wsf;             // 8,000,000 bf16 = 4,000,000 f  [N][160]
  float*   A0    = wsf + 4000000;            // 1,000,000  [N][20]
  float*   A1    = wsf + 5000000;            // 1,000,000
  float*   XPRE  = wsf + 6000000;            // 1,000,000
  float*   FCS   = wsf + 7000000;            // 4,000,000  [4][N][20]
  __bf16*  B0bf  = (__bf16*)(wsf + 11000000);//   322,560 bf16 = 161,280 f
  float*   BIAS0 = wsf + 11161280;           //       160
  float*   WL    = wsf + 11161440;           //     9,600  3x[20][160]
  float*   BIASL = wsf + 11171040;           //       480
  float*   BN    = wsf + 11171520;           //       320  4x{sum20,sq20,mu20,rs20}
  int*     ib    = (int*)(wsf + 11171840);
  int* DEG  = ib;                            // 100,000  [2][N]
  int* RP0  = ib + 100000;                   //  50,004
  int* RP1  = ib + 150004;                   //  50,004
  int* NX0  = ib + 200008;                   //  50,000
  int* NX1  = ib + 250008;                   //  50,000
  int* ADJ0 = ib + 300008;                   // 1,600,000
  int* ADJ1 = ib + 1900008;                  // 1,600,000

  // pack weights + zero accumulators/degrees
  const int packN = NCOL*KPAD + 160 + 9600 + 480 + 320 + 2*N_NODES;  // 433,120
  pack_kernel<<<(packN + 255)/256, 256, 0, stream>>>(
      W0q, W0k, W0v, W0s, b0q, b0k, b0v, b0s,
      Wq, Wk, Wv, Ws_, bq, bk, bv, bs_,
      B0bf, BIAS0, WL, BIASL, BN, DEG);

  // CSR by dst, per edge type (indices identical across layers)
  hist_kernel<<<(2*E_EDGES + 255)/256, 256, 0, stream>>>(same, diff, DEG);
  scan_kernel<<<2, 1024, 0, stream>>>(DEG, RP0, RP1, NX0, NX1);
  {
    const long nchunk = (2L*E_EDGES + SC_CHUNK - 1) / SC_CHUNK;
    scatter_kernel<<<(int)(nchunk*8), 256, 0, stream>>>(same, diff, NX0, NX1, ADJ0, ADJ1);
  }

  dim3 attn_grid((N_NODES + 15)/16, 2);

  for (int l = 0; l < 4; l++) {
    if (l == 0)
      gemm0_mfma<<<(N_NODES + 127)/128, 512, 0, stream>>>(feat, B0bf, BIAS0, PROJ);
    else
      proj_small_kernel<<<(N_NODES + 15)/16, 256, 0, stream>>>(
          FCS + (size_t)(l-1)*N_NODES*D, WL + (size_t)(l-1)*3200, BIASL + (size_t)(l-1)*160, PROJ);

    attn_kernel<<<attn_grid, 256, 0, stream>>>(RP0, ADJ0, RP1, ADJ1, PROJ, A0, A1);

    combine_kernel<<<(N_NODES*D + 255)/256, 256, 0, stream>>>(A0, A1, w1, w2, l, XPRE, BN + l*80);
    stats_kernel<<<1, 64, 0, stream>>>(BN + l*80);
    bnapply_kernel<<<(N_NODES*D + 255)/256, 256, 0, stream>>>(
        XPRE, BN + l*80, gamma, beta, l, FCS + (size_t)l*N_NODES*D);
  }

  final_kernel<<<(N_NODES + 255)/256, 256, 0, stream>>>(FCS, Wout, bout, (float*)d_out);
}

// Round 4
// 1098.826 us; speedup vs baseline: 2.2039x; 1.0675x over previous
//
#include <hip/hip_runtime.h>
#include <math.h>

#define N_NODES 50000
#define E_EDGES 1600000
#define F_IN    2000
#define D       20
#define NCOL    160   // 2 edge types * [q s k v] * 20  (col order: q,s,k,v per edge type)
#define KPAD    2016  // 63 * 32

#define INV_SQRT_D 0.22360679774997896f

typedef __bf16 bf16x8 __attribute__((ext_vector_type(8)));
typedef __bf16 bf16x4 __attribute__((ext_vector_type(4)));
typedef float  f32x4  __attribute__((ext_vector_type(4)));

// ---------------- pack weights + zero accumulators --------------------------------------
// Column order within each 80-col edge-type block: q(0-19) s(20-39) k(40-59) v(60-79)
// -> attention gathers k+v as one 80B 16B-aligned chunk.
__global__ void pack_kernel(
    const float* __restrict__ W0q, const float* __restrict__ W0k,
    const float* __restrict__ W0v, const float* __restrict__ W0s,
    const float* __restrict__ b0q, const float* __restrict__ b0k,
    const float* __restrict__ b0v, const float* __restrict__ b0s,
    const float* __restrict__ Wq,  const float* __restrict__ Wk,
    const float* __restrict__ Wv,  const float* __restrict__ Ws_,
    const float* __restrict__ bq,  const float* __restrict__ bk,
    const float* __restrict__ bv,  const float* __restrict__ bs_,
    __bf16* __restrict__ B0, float* __restrict__ bias0,
    float* __restrict__ WL, float* __restrict__ biasL,
    float* __restrict__ bn, int* __restrict__ deg)
{
  long idx = (long)blockIdx.x * blockDim.x + threadIdx.x;
  if (idx < (long)NCOL*KPAD) {              // B0T: [160][2016] bf16
    int col = (int)(idx / KPAD), k = (int)(idx % KPAD);
    int et = col / 80, r = col % 80, mat = r / 20, d = r % 20;
    const float* w = (mat==0)?W0q:(mat==1)?W0s:(mat==2)?W0k:W0v;
    float v = (k < F_IN) ? w[((size_t)et*F_IN + k)*D + d] : 0.f;
    B0[idx] = (__bf16)v;
    return;
  }
  idx -= (long)NCOL*KPAD;
  if (idx < 160) {                          // bias0
    int col = (int)idx;
    int et = col / 80, r = col % 80, mat = r / 20, d = r % 20;
    const float* b = (mat==0)?b0q:(mat==1)?b0s:(mat==2)?b0k:b0v;
    bias0[col] = b[et*D + d];
    return;
  }
  idx -= 160;
  if (idx < 9600) {                         // WL: 3 x [20][160]
    int l = (int)(idx / 3200), rem = (int)(idx % 3200);
    int k = rem / NCOL, col = rem % NCOL;
    int et = col / 80, r = col % 80, mat = r / 20, d = r % 20;
    const float* w = (mat==0)?Wq:(mat==1)?Ws_:(mat==2)?Wk:Wv;
    WL[idx] = w[(((size_t)l*2 + et)*D + k)*D + d];
    return;
  }
  idx -= 9600;
  if (idx < 480) {                          // biasL: 3 x [160]
    int l = (int)(idx / NCOL), col = (int)(idx % NCOL);
    int et = col / 80, r = col % 80, mat = r / 20, d = r % 20;
    const float* b = (mat==0)?bq:(mat==1)?bs_:(mat==2)?bk:bv;
    biasL[idx] = b[(l*2 + et)*D + d];
    return;
  }
  idx -= 480;
  if (idx < 320) { bn[idx] = 0.f; return; } // BN accumulators, 4 layers x 80
  idx -= 320;
  if (idx < 2*N_NODES) { deg[idx] = 0; return; }
}

// ---------------- CSR build (indices static across layers -> build once per call) -------
__global__ void hist_kernel(const int* __restrict__ same, const int* __restrict__ diff,
                            int* __restrict__ deg)
{
  long i = (long)blockIdx.x * blockDim.x + threadIdx.x;
  if (i >= 2L*E_EDGES) return;
  int et = (i >= E_EDGES) ? 1 : 0;
  long e = i - (long)et*E_EDGES;
  const int* ix = et ? diff : same;
  int dst = ix[E_EDGES + e];
  atomicAdd(&deg[(size_t)et*N_NODES + dst], 1);
}

__global__ void scan_kernel(const int* __restrict__ deg,
                            int* __restrict__ rowptr0, int* __restrict__ rowptr1,
                            int* __restrict__ next0, int* __restrict__ next1)
{
  const int et = blockIdx.x;
  const int* dg = deg + (size_t)et*N_NODES;
  int* rp = et ? rowptr1 : rowptr0;
  int* np = et ? next1 : next0;
  __shared__ int part[1024];
  const int t = threadIdx.x;
  const int per = (N_NODES + 1023) / 1024;  // 49
  const int b = t * per;
  const int e = (b + per < N_NODES) ? (b + per) : N_NODES;
  int s = 0;
  for (int i = b; i < e; i++) s += dg[i];
  part[t] = s;
  __syncthreads();
  for (int o = 1; o < 1024; o <<= 1) {
    int v = (t >= o) ? part[t-o] : 0;
    __syncthreads();
    part[t] += v;
    __syncthreads();
  }
  int run = (t == 0) ? 0 : part[t-1];
  for (int i = b; i < e; i++) {
    rp[i] = run; np[i] = run;
    run += dg[i];
  }
  if (t == 0) rp[N_NODES] = part[1023];
}

// XCD-partitioned scatter: partition p (= blockIdx&7, default round-robin XCD mapping)
// owns dst range [p*6250,(p+1)*6250) so each adj cache line is dirtied from one XCD.
#define SC_EPT 16
#define SC_CHUNK (256*SC_EPT)
__global__ void scatter_kernel(const int* __restrict__ same, const int* __restrict__ diff,
                               int* __restrict__ next0, int* __restrict__ next1,
                               int* __restrict__ adj0, int* __restrict__ adj1)
{
  const int part  = blockIdx.x & 7;
  const int chunk = blockIdx.x >> 3;
  const int lo = part * (N_NODES/8);
  const int hi = lo + (N_NODES/8);
  const long i0 = (long)chunk * SC_CHUNK + threadIdx.x;
#pragma unroll
  for (int it = 0; it < SC_EPT; ++it) {
    long i = i0 + (long)it*256;
    if (i >= 2L*E_EDGES) break;
    int et = (i >= E_EDGES) ? 1 : 0;
    long e = i - (long)et*E_EDGES;
    const int* ix = et ? diff : same;
    int dst = ix[E_EDGES + e];
    if (dst >= lo && dst < hi) {
      int src = ix[e];
      int* np  = et ? next1 : next0;
      int* adj = et ? adj1  : adj0;
      int pos = atomicAdd(&np[dst], 1);
      adj[pos] = src;
    }
  }
}

// ---------------- layer-0 MFMA GEMM: [50000,2000]fp32 -> bf16 @ [2016,160]bf16 ----------
__launch_bounds__(512)
__global__ void gemm0_mfma(const float* __restrict__ A,
                           const __bf16* __restrict__ Bt,
                           const float* __restrict__ bias,
                           __bf16* __restrict__ C)
{
  __shared__ __bf16 as[128*32];
  const int t    = threadIdx.x;
  const int lane = t & 63;
  const int wid  = t >> 6;
  const int wr   = wid >> 1;        // 0..3 -> rows wr*32
  const int wc   = wid & 1;         // 0..1 -> cols wc*80
  const int rb0  = blockIdx.x * 128;

  const int srow = t >> 2;          // staging: row 0..127
  const int skc  = (t & 3) * 8;     // k chunk of 8
  const int arow = rb0 + srow;
  const float* aptr = A + (size_t)arow * F_IN;

  const int lrow = lane & 15;       // frag row/col within 16
  const int lkb  = (lane >> 4) * 8; // k sub-block

  f32x4 acc[2][5];
#pragma unroll
  for (int i = 0; i < 2; i++)
#pragma unroll
    for (int j = 0; j < 5; j++) acc[i][j] = (f32x4){0.f,0.f,0.f,0.f};

  float4 p0, p1;
  auto loadA = [&](int k0) {
    int k = k0 + skc;
    if (arow < N_NODES) {
      if (k + 8 <= F_IN) {
        p0 = *(const float4*)(aptr + k);
        p1 = *(const float4*)(aptr + k + 4);
      } else {
        float tmp[8];
#pragma unroll
        for (int i = 0; i < 8; i++) tmp[i] = (k + i < F_IN) ? aptr[k + i] : 0.f;
        p0 = make_float4(tmp[0],tmp[1],tmp[2],tmp[3]);
        p1 = make_float4(tmp[4],tmp[5],tmp[6],tmp[7]);
      }
    } else {
      p0 = make_float4(0,0,0,0); p1 = p0;
    }
  };

  loadA(0);
  for (int s = 0; s < 63; s++) {
    bf16x8 h;
    h[0]=(__bf16)p0.x; h[1]=(__bf16)p0.y; h[2]=(__bf16)p0.z; h[3]=(__bf16)p0.w;
    h[4]=(__bf16)p1.x; h[5]=(__bf16)p1.y; h[6]=(__bf16)p1.z; h[7]=(__bf16)p1.w;
    *(bf16x8*)&as[srow*32 + skc] = h;
    __syncthreads();
    if (s + 1 < 63) loadA((s + 1) * 32);

    bf16x8 af[2];
#pragma unroll
    for (int rf = 0; rf < 2; rf++)
      af[rf] = *(bf16x8*)&as[(wr*32 + rf*16 + lrow)*32 + lkb];
    bf16x8 bfr[5];
#pragma unroll
    for (int cf = 0; cf < 5; cf++)
      bfr[cf] = *(const bf16x8*)(Bt + (size_t)(wc*80 + cf*16 + lrow)*KPAD + s*32 + lkb);
#pragma unroll
    for (int rf = 0; rf < 2; rf++)
#pragma unroll
      for (int cf = 0; cf < 5; cf++)
        acc[rf][cf] = __builtin_amdgcn_mfma_f32_16x16x32_bf16(af[rf], bfr[cf], acc[rf][cf], 0, 0, 0);
    __syncthreads();
  }

  // epilogue: C/D layout col=lane&15, row=(lane>>4)*4 + j ; C is bf16 [N][160]
#pragma unroll
  for (int rf = 0; rf < 2; rf++) {
#pragma unroll
    for (int cf = 0; cf < 5; cf++) {
      int col = wc*80 + cf*16 + lrow;
      float bv = bias[col];
#pragma unroll
      for (int j = 0; j < 4; j++) {
        int r = rb0 + wr*32 + rf*16 + (lane >> 4)*4 + j;
        if (r < N_NODES) C[(size_t)r*NCOL + col] = (__bf16)(acc[rf][cf][j] + bv);
      }
    }
  }
}

// ---------------- layers 1..3 projection: [N,20]fp32 @ [20,160]fp32 -> bf16 -------------
__launch_bounds__(256)
__global__ void proj_small_kernel(const float* __restrict__ x, const float* __restrict__ W,
                                  const float* __restrict__ bias, __bf16* __restrict__ C)
{
  __shared__ float ws[20*160];
  __shared__ float xs[16*20];
  const int t = threadIdx.x;
  const int n0 = blockIdx.x * 16;
#pragma unroll
  for (int i = 0; i < 13; i++) {
    int idx = t + i*256;
    if (idx < 3200) ws[idx] = W[idx];
  }
#pragma unroll
  for (int i = 0; i < 2; i++) {
    int idx = t + i*256;
    if (idx < 320) {
      int nl = idx / 20, k = idx % 20;
      int n = n0 + nl;
      xs[idx] = (n < N_NODES) ? x[(size_t)n*D + k] : 0.f;
    }
  }
  __syncthreads();
#pragma unroll
  for (int i = 0; i < 10; i++) {
    int idx = t + i*256;
    int nl = idx / NCOL, col = idx % NCOL;
    int n = n0 + nl;
    if (n < N_NODES) {
      float acc = bias[col];
#pragma unroll
      for (int k = 0; k < 20; k++) acc += xs[nl*20 + k] * ws[k*NCOL + col];
      C[(size_t)n*NCOL + col] = (__bf16)acc;
    }
  }
}

// ---------------- fused attention (both ets) + combine + BN partial sums ----------------
// 16 lanes per node; paired-edge online softmax (one rescale per 2 edges).
__launch_bounds__(256)
__global__ void attn_fused(const int* __restrict__ rp0, const int* __restrict__ adj0,
                           const int* __restrict__ rp1, const int* __restrict__ adj1,
                           const __bf16* __restrict__ proj,
                           const float* __restrict__ w1, const float* __restrict__ w2, int l,
                           float* __restrict__ xpre, float* __restrict__ bn)
{
  __shared__ float ls[40];
  const int t  = threadIdx.x;
  const int sl = t & 15;
  const int node = blockIdx.x*16 + (t >> 4);
  const bool valid = node < N_NODES;
  if (t < 40) ls[t] = 0.f;
  __syncthreads();

  const float wa = w1[l], wb = w2[l];
  const float cw[2] = { wa/(wa+wb), wb/(wa+wb) };
  float xacc[20];           // meaningful in lane sl==0 only

#pragma unroll
  for (int et = 0; et < 2; et++) {
    float m = -INFINITY, z = 0.f;
    float S[20];
#pragma unroll
    for (int d = 0; d < 20; d++) S[d] = 0.f;

    const __bf16* rq = proj + (size_t)(valid ? node : 0)*NCOL + et*80;

    if (valid) {
      float qf[20];
      {
        bf16x8 q0 = *(const bf16x8*)(rq);
        bf16x8 q1 = *(const bf16x8*)(rq + 8);
        bf16x4 q2 = *(const bf16x4*)(rq + 16);
#pragma unroll
        for (int i = 0; i < 8; i++) { qf[i] = (float)q0[i]; qf[8+i] = (float)q1[i]; }
#pragma unroll
        for (int i = 0; i < 4; i++) qf[16+i] = (float)q2[i];
      }
      const int* rowptr = et ? rp1 : rp0;
      const int* adj    = et ? adj1 : adj0;
      const int beg = rowptr[node], end = rowptr[node+1];

      int i = beg + sl;
      // paired loop: 2 edges per iteration, single rescale
      for (; i + 16 < end; i += 32) {
        const int s0 = adj[i], s1 = adj[i+16];
        const __bf16* kva = proj + (size_t)s0*NCOL + et*80 + 40;
        const __bf16* kvb = proj + (size_t)s1*NCOL + et*80 + 40;
        bf16x8 a0 = *(const bf16x8*)(kva);
        bf16x8 a1 = *(const bf16x8*)(kva + 8);
        bf16x8 a2 = *(const bf16x8*)(kva + 16);
        bf16x8 a3 = *(const bf16x8*)(kva + 24);
        bf16x8 a4 = *(const bf16x8*)(kva + 32);
        bf16x8 b0 = *(const bf16x8*)(kvb);
        bf16x8 b1 = *(const bf16x8*)(kvb + 8);
        bf16x8 b2 = *(const bf16x8*)(kvb + 16);
        bf16x8 b3 = *(const bf16x8*)(kvb + 24);
        bf16x8 b4 = *(const bf16x8*)(kvb + 32);

        float d0 = 0.f, d1 = 0.f;
#pragma unroll
        for (int j = 0; j < 8; j++) { d0 += qf[j]*(float)a0[j];     d1 += qf[j]*(float)b0[j]; }
#pragma unroll
        for (int j = 0; j < 8; j++) { d0 += qf[8+j]*(float)a1[j];   d1 += qf[8+j]*(float)b1[j]; }
#pragma unroll
        for (int j = 0; j < 4; j++) { d0 += qf[16+j]*(float)a2[j];  d1 += qf[16+j]*(float)b2[j]; }
        d0 *= INV_SQRT_D; d1 *= INV_SQRT_D;

        float nm = fmaxf(fmaxf(m, d0), d1);
        float a  = __expf(m - nm);       // m=-inf first iter -> 0
        float w0 = __expf(d0 - nm);
        float w1v= __expf(d1 - nm);
        z = z*a + w0 + w1v;
#pragma unroll
        for (int d = 0; d < 4; d++) S[d]    = S[d]*a    + w0*(float)a2[4+d] + w1v*(float)b2[4+d];
#pragma unroll
        for (int d = 0; d < 8; d++) S[4+d]  = S[4+d]*a  + w0*(float)a3[d]   + w1v*(float)b3[d];
#pragma unroll
        for (int d = 0; d < 8; d++) S[12+d] = S[12+d]*a + w0*(float)a4[d]   + w1v*(float)b4[d];
        m = nm;
      }
      // tail (at most one edge per lane)
      for (; i < end; i += 16) {
        const int s0 = adj[i];
        const __bf16* kva = proj + (size_t)s0*NCOL + et*80 + 40;
        bf16x8 a0 = *(const bf16x8*)(kva);
        bf16x8 a1 = *(const bf16x8*)(kva + 8);
        bf16x8 a2 = *(const bf16x8*)(kva + 16);
        bf16x8 a3 = *(const bf16x8*)(kva + 24);
        bf16x8 a4 = *(const bf16x8*)(kva + 32);
        float d0 = 0.f;
#pragma unroll
        for (int j = 0; j < 8; j++) d0 += qf[j]*(float)a0[j];
#pragma unroll
        for (int j = 0; j < 8; j++) d0 += qf[8+j]*(float)a1[j];
#pragma unroll
        for (int j = 0; j < 4; j++) d0 += qf[16+j]*(float)a2[j];
        d0 *= INV_SQRT_D;
        float nm = fmaxf(m, d0);
        float a  = __expf(m - nm);
        float w0 = __expf(d0 - nm);
        z = z*a + w0;
#pragma unroll
        for (int d = 0; d < 4; d++) S[d]    = S[d]*a    + w0*(float)a2[4+d];
#pragma unroll
        for (int d = 0; d < 8; d++) S[4+d]  = S[4+d]*a  + w0*(float)a3[d];
#pragma unroll
        for (int d = 0; d < 8; d++) S[12+d] = S[12+d]*a + w0*(float)a4[d];
        m = nm;
      }
    }

    // merge 16 lanes; fminf guards -inf - -inf = NaN (also handles invalid nodes)
#pragma unroll
    for (int o = 8; o >= 1; o >>= 1) {
      float m2 = __shfl_xor(m, o, 64);
      float z2 = __shfl_xor(z, o, 64);
      float nm = fmaxf(m, m2);
      float a  = __expf(fminf(m  - nm, 0.f));
      float b  = __expf(fminf(m2 - nm, 0.f));
      z = z*a + z2*b;
#pragma unroll
      for (int d = 0; d < 20; d++) {
        float s2 = __shfl_xor(S[d], o, 64);
        S[d] = S[d]*a + s2*b;
      }
      m = nm;
    }

    if (valid && sl == 0) {
      const float inv = 1.f / (z + 1e-16f);
      const __bf16* sp = rq + 20;          // skip term x@Ws+bs at +20
      float sv[20];
      {
        bf16x4 s0 = *(const bf16x4*)(sp);
        bf16x8 s1 = *(const bf16x8*)(sp + 4);
        bf16x8 s2 = *(const bf16x8*)(sp + 12);
#pragma unroll
        for (int i = 0; i < 4; i++) sv[i] = (float)s0[i];
#pragma unroll
        for (int i = 0; i < 8; i++) { sv[4+i] = (float)s1[i]; sv[12+i] = (float)s2[i]; }
      }
      const float c = cw[et];
#pragma unroll
      for (int d = 0; d < 20; d++) {
        float val = c * (S[d]*inv + sv[d]);
        xacc[d] = (et == 0) ? val : (xacc[d] + val);
      }
    }
  }

  if (valid && sl == 0) {
    float* xo = xpre + (size_t)node*D;
#pragma unroll
    for (int j = 0; j < 5; j++) {
      float4 o4 = make_float4(xacc[4*j], xacc[4*j+1], xacc[4*j+2], xacc[4*j+3]);
      *(float4*)(xo + 4*j) = o4;
    }
#pragma unroll
    for (int d = 0; d < 20; d++) {
      atomicAdd(&ls[d], xacc[d]);
      atomicAdd(&ls[20+d], xacc[d]*xacc[d]);
    }
  }
  __syncthreads();
  if (t < 40) atomicAdd(&bn[t], ls[t]);
}

// ---------------- BN apply (stats inlined from sums) + leaky ReLU -----------------------
__global__ void bnapply_kernel(const float* __restrict__ xpre, const float* __restrict__ bn,
                               const float* __restrict__ gamma, const float* __restrict__ beta,
                               int l, float* __restrict__ out)
{
  const int i = blockIdx.x*256 + threadIdx.x;
  if (i >= N_NODES*D) return;
  const int d = i % D;
  const float mu  = bn[d] * (1.f/N_NODES);
  const float var = bn[20+d] * (1.f/N_NODES) - mu*mu;
  const float rs  = rsqrtf(var + 1e-5f);
  float v = (xpre[i] - mu) * rs * gamma[l*D+d] + beta[l*D+d];
  out[i] = (v > 0.f) ? v : 0.01f*v;
}

// ---------------- final: concat(fcs) @ Wout + bout --------------------------------------
__global__ void final_kernel(const float* __restrict__ fcs, const float* __restrict__ Wout,
                             const float* __restrict__ bout, float* __restrict__ out)
{
  const int n = blockIdx.x*256 + threadIdx.x;
  if (n >= N_NODES) return;
  float a0 = bout[0], a1 = bout[1];
#pragma unroll
  for (int l = 0; l < 4; l++) {
    const float* base = fcs + (size_t)l*N_NODES*D + (size_t)n*D;
#pragma unroll
    for (int d = 0; d < D; d++) {
      float v = base[d];
      a0 += v * Wout[(l*D+d)*2 + 0];
      a1 += v * Wout[(l*D+d)*2 + 1];
    }
  }
  out[n*2+0] = a0;
  out[n*2+1] = a1;
}

// ----------------------------------------------------------------------------------------
extern "C" void kernel_launch(void* const* d_in, const int* in_sizes, int n_in,
                              void* d_out, int out_size, void* d_ws, size_t ws_size,
                              hipStream_t stream)
{
  const float* feat = (const float*)d_in[0];
  const int*   same = (const int*)d_in[1];
  const int*   diff = (const int*)d_in[2];
  const float* W0q = (const float*)d_in[3];
  const float* b0q = (const float*)d_in[4];
  const float* W0k = (const float*)d_in[5];
  const float* b0k = (const float*)d_in[6];
  const float* W0v = (const float*)d_in[7];
  const float* b0v = (const float*)d_in[8];
  const float* W0s = (const float*)d_in[9];
  const float* b0s = (const float*)d_in[10];
  const float* Wq  = (const float*)d_in[11];
  const float* bq  = (const float*)d_in[12];
  const float* Wk  = (const float*)d_in[13];
  const float* bk  = (const float*)d_in[14];
  const float* Wv  = (const float*)d_in[15];
  const float* bv  = (const float*)d_in[16];
  const float* Ws_ = (const float*)d_in[17];
  const float* bs_ = (const float*)d_in[18];
  const float* w1  = (const float*)d_in[19];
  const float* w2  = (const float*)d_in[20];
  const float* gamma = (const float*)d_in[21];
  const float* beta  = (const float*)d_in[22];
  const float* Wout  = (const float*)d_in[23];
  const float* bout  = (const float*)d_in[24];

  float* wsf  = (float*)d_ws;
  __bf16*  PROJ  = (__bf16*)wsf;             // 8,000,000 bf16 = 4,000,000 f  [N][160]
  float*   XPRE  = wsf + 6000000;            // 1,000,000
  float*   FCS   = wsf + 7000000;            // 4,000,000  [4][N][20]
  __bf16*  B0bf  = (__bf16*)(wsf + 11000000);//   322,560 bf16 = 161,280 f
  float*   BIAS0 = wsf + 11161280;           //       160
  float*   WL    = wsf + 11161440;           //     9,600  3x[20][160]
  float*   BIASL = wsf + 11171040;           //       480
  float*   BN    = wsf + 11171520;           //       320  4x{sum20,sq20,unused40}
  int*     ib    = (int*)(wsf + 11171840);
  int* DEG  = ib;                            // 100,000  [2][N]
  int* RP0  = ib + 100000;                   //  50,004
  int* RP1  = ib + 150004;                   //  50,004
  int* NX0  = ib + 200008;                   //  50,000
  int* NX1  = ib + 250008;                   //  50,000
  int* ADJ0 = ib + 300008;                   // 1,600,000
  int* ADJ1 = ib + 1900008;                  // 1,600,000

  // pack weights + zero accumulators/degrees
  const int packN = NCOL*KPAD + 160 + 9600 + 480 + 320 + 2*N_NODES;  // 433,120
  pack_kernel<<<(packN + 255)/256, 256, 0, stream>>>(
      W0q, W0k, W0v, W0s, b0q, b0k, b0v, b0s,
      Wq, Wk, Wv, Ws_, bq, bk, bv, bs_,
      B0bf, BIAS0, WL, BIASL, BN, DEG);

  // CSR by dst, per edge type (indices identical across layers)
  hist_kernel<<<(2*E_EDGES + 255)/256, 256, 0, stream>>>(same, diff, DEG);
  scan_kernel<<<2, 1024, 0, stream>>>(DEG, RP0, RP1, NX0, NX1);
  {
    const long nchunk = (2L*E_EDGES + SC_CHUNK - 1) / SC_CHUNK;
    scatter_kernel<<<(int)(nchunk*8), 256, 0, stream>>>(same, diff, NX0, NX1, ADJ0, ADJ1);
  }

  for (int l = 0; l < 4; l++) {
    if (l == 0)
      gemm0_mfma<<<(N_NODES + 127)/128, 512, 0, stream>>>(feat, B0bf, BIAS0, PROJ);
    else
      proj_small_kernel<<<(N_NODES + 15)/16, 256, 0, stream>>>(
          FCS + (size_t)(l-1)*N_NODES*D, WL + (size_t)(l-1)*3200, BIASL + (size_t)(l-1)*160, PROJ);

    attn_fused<<<(N_NODES + 15)/16, 256, 0, stream>>>(
        RP0, ADJ0, RP1, ADJ1, PROJ, w1, w2, l, XPRE, BN + l*80);

    bnapply_kernel<<<(N_NODES*D + 255)/256, 256, 0, stream>>>(
        XPRE, BN + l*80, gamma, beta, l, FCS + (size_t)l*N_NODES*D);
  }

  final_kernel<<<(N_NODES + 255)/256, 256, 0, stream>>>(FCS, Wout, bout, (float*)d_out);
}